// Round 17
// baseline (1108.821 us; speedup 1.0000x reference)
//
#include <hip/hip_runtime.h>
#include <hip/hip_bf16.h>
#include <hip/hip_fp16.h>
#include <stdint.h>

#define TLEN 512
#define TCW 96
#define NCHK 6                        // 5 chunks of 96 + 1 of 32
__device__ __forceinline__ int csize(int i){ return (i == 5) ? 32 : 96; }

typedef unsigned short u16;
typedef unsigned int u32;

__device__ __forceinline__ float b2f(u16 u){ union{u32 i; float f;} v; v.i = ((u32)u)<<16; return v.f; }
__device__ __forceinline__ u16 f2bf(float f){
    union{float f; u32 i;} v; v.f = f;
    u32 b = v.i; b += 0x7fffu + ((b>>16)&1u);   // RNE
    return (u16)(b>>16);
}
__device__ __forceinline__ float fexp2(float x){ return __builtin_amdgcn_exp2f(x); }
__device__ __forceinline__ float frcp(float x){ return __builtin_amdgcn_rcpf(x); }
#define LOG2E 1.4426950408889634f
__device__ __forceinline__ float elu_f(float x){ return x > 0.f ? x : fexp2(x*LOG2E) - 1.f; }
__device__ __forceinline__ float sigm(float x){ return frcp(1.f + fexp2(-LOG2E*x)); }
__device__ __forceinline__ float tanh_f(float x){ return 1.f - 2.f*frcp(1.f + fexp2((2.f*LOG2E)*x)); }

// dtype-adaptive load: F=true -> float32 buffer, else bf16 buffer
__device__ __forceinline__ float ldg(const void* p, int i, bool F){
    return F ? ((const float*)p)[i] : b2f(((const u16*)p)[i]);
}

__device__ void fill(float* dst, const void* src, int n, int tid, int nt, bool F){
    for (int i = tid; i < n; i += nt) dst[i] = ldg(src, i, F);
}
__device__ void fillS(float* dst, const void* src, int R, int C, int stride, int tid, int nt, bool F){
    for (int i = tid; i < R*C; i += nt){ int r = i / C, c = i % C; dst[i] = ldg(src, r*stride + c, F); }
}
// transposed: dst[i*K+k] = src[k*stride+i]
__device__ void fillT(float* dst, const void* src, int K, int I, int stride, int tid, int nt, bool F){
    for (int idx = tid; idx < K*I; idx += nt){ int i = idx / K, k = idx % K; dst[idx] = ldg(src, k*stride + i, F); }
}

// 256 threads, 4 waves: wave 0 lanes 0-31 = GRU scan for 2 b (16 lanes/b, all gates
// per lane); waves 1-3 = MLP (192 threads = 2b x 96t slots). Block owns 2 b;
// 512 blocks -> 2 blocks/CU co-residency (LDS ~78.7 KB, zero scratch).
__global__ __launch_bounds__(256,1) void fused(
    const void* envs, const void* states,
    const void* se_W0, const void* se_b0, const void* se_Wh, const void* se_bh, const void* se_Wo, const void* se_bo,
    const void* oe_W0, const void* oe_b0, const void* oe_Wh, const void* oe_bh, const void* oe_Wo, const void* oe_bo,
    const void* null_embed, const void* init_h,
    const void* att_W0, const void* att_b0, const void* att_Wh, const void* att_bh, const void* att_Wo, const void* att_bo,
    const void* gru0_Wi, const void* gru0_Wh, const void* gru0_bi, const void* gru0_bh,
    const void* gru1_Wi, const void* gru1_Wh, const void* gru1_bi, const void* gru1_bh,
    const void* rel_W0, const void* rel_b0, const void* rel_Wh, const void* rel_bh, const void* rel_Wo, const void* rel_bo,
    const void* fin_W0, const void* fin_b0, const void* fin_Wh, const void* fin_bh, const void* fin_Wo, const void* fin_bo,
    void* out)
{
    // persistent LDS weights
    __shared__ float sW0T[64], sb0[16], sWhT[768], sbh[48], sWoT[256], sbo[16];
    __shared__ float aW0T[256], aWhT[512], abh[32], aWo[16], abo_s[1];
    __shared__ float wi0se[768];
    __shared__ float rW0T[896], rWhT[448], rbh[56], rWoT[448], rbo[56];
    __shared__ float fW0T[288], fb0[4], fWhT[16], fbh[4], fWoT[16], fbo[4];
    __shared__ float E_att[224], E_rel[112], base_xi[96];
    __shared__ float g0bhn[16], g1bi48[48], g1bh48[48];  // scan biases
    // uni (56 KB): one-time phase-0 buffers, then pipeline buffers
    __shared__ float uni[14016];
    __shared__ int s_isf32;

    const int tid = threadIdx.x, nt = 256;
    const int blk = blockIdx.x;
    const int wid = tid >> 6, ln = tid & 63;

    // pipeline buffer views (fp16) inside uni
    _Float16* bufA = (_Float16*)(uni);           // 2b x 96t x 48 = 9216 h
    _Float16* bufB = (_Float16*)(uni + 4608);
    _Float16* gruA = (_Float16*)(uni + 9216);    // 2b x 96t x 16 = 3072 h
    _Float16* gruB = (_Float16*)(uni + 10752);
    _Float16* cscA = (_Float16*)(uni + 12288);   // 2b x 7s x 96t = 1344 h (unnormalized exp)
    _Float16* cscB = (_Float16*)(uni + 12960);
    float*    invA = uni + 13632;                // 2b x 96t = 192 f
    float*    invB = uni + 13824;

    // ---------------- dtype detection (uniform, deterministic) ----------------
    if (tid == 0){
        const u16* p = (const u16*)se_W0;
        int ok = 1;
        #pragma unroll
        for (int k = 0; k < 8; k++){
            float v = fabsf(b2f(p[2*k]));
            ok &= (v > 1e-12f && v < 16.f) ? 1 : 0;
        }
        s_isf32 = ok ? 0 : 1;
    }
    __syncthreads();
    const bool F = (s_isf32 != 0);

    // ---------------- phase 0a: stage weights ----------------
    fillT(sW0T, se_W0, 4, 16, 16, tid, nt, F);
    fill (sb0, se_b0, 16, tid, nt, F);
    for (int l = 0; l < 3; l++) fillT(sWhT + l*256, (const u16*)se_Wh + (F?l*512:l*256), 16, 16, 16, tid, nt, F);
    fill (sbh, se_bh, 48, tid, nt, F);
    fillT(sWoT, se_Wo, 16, 16, 16, tid, nt, F);
    fill (sbo, se_bo, 16, tid, nt, F);
    fillT(aW0T, att_W0, 16, 16, 16, tid, nt, F);                 // se rows 0..15
    for (int l = 0; l < 2; l++) fillT(aWhT + l*256, (const u16*)att_Wh + (F?l*512:l*256), 16, 16, 16, tid, nt, F);
    fill (abh, att_bh, 32, tid, nt, F);
    fill (aWo, att_Wo, 16, tid, nt, F);
    fill (abo_s, att_bo, 1, tid, nt, F);
    fillS(wi0se, gru0_Wi, 48, 16, 128, tid, nt, F);              // se cols of Wi0
    for (int s = 0; s < 7; s++){
        fillT(rW0T + s*128, (const u16*)rel_W0 + (F?s*512:s*256), 16, 8, 8, tid, nt, F);   // gru rows 0..15
        fillT(rWhT + s*64, (const u16*)rel_Wh + (F?s*128:s*64), 8, 8, 8, tid, nt, F);
        fillT(rWoT + s*64, (const u16*)rel_Wo + (F?s*128:s*64), 8, 8, 8, tid, nt, F);
    }
    fill (rbh, rel_bh, 56, tid, nt, F);
    fill (rbo, rel_bo, 56, tid, nt, F);
    fillT(fW0T, fin_W0, 72, 4, 4, tid, nt, F);
    fill (fb0, fin_b0, 4, tid, nt, F);
    fillT(fWhT, fin_Wh, 4, 4, 4, tid, nt, F);
    fill (fbh, fin_bh, 4, tid, nt, F);
    fillT(fWoT, fin_Wo, 4, 4, 4, tid, nt, F);
    fill (fbo, fin_bo, 4, tid, nt, F);
    fill (g0bhn, (const u16*)gru0_bh + (F?64:32), 16, tid, nt, F);  // bh0_n
    fill (g1bi48, gru1_bi, 48, tid, nt, F);
    fill (g1bh48, gru1_bh, 48, tid, nt, F);
    // one-time buffers inside uni (4848 floats, dead before pipeline starts)
    float* oeW0T = uni;         // 144
    float* oeb0  = uni + 144;   // 48
    float* oeWhT = uni + 192;   // 2304
    float* oebh  = uni + 2496;  // 144
    float* oeWoT = uni + 2640;  // 768
    float* oebo  = uni + 3408;  // 48
    float* aW0To = uni + 3456;  // 256
    float* ab0   = uni + 3712;  // 16
    float* rW0To = uni + 3728;  // 896
    float* objE  = uni + 4624;  // 224 (2b x 7s x 16)
    for (int s = 0; s < 3; s++){
        fillT(oeW0T + s*48, (const u16*)oe_W0 + (F?s*96:s*48), 3, 16, 16, tid, nt, F);
        for (int l = 0; l < 3; l++)
            fillT(oeWhT + (s*3+l)*256, (const u16*)oe_Wh + (F?(s*3+l)*512:(s*3+l)*256), 16, 16, 16, tid, nt, F);
        fillT(oeWoT + s*256, (const u16*)oe_Wo + (F?s*512:s*256), 16, 16, 16, tid, nt, F);
    }
    fill(oeb0, oe_b0, 48, tid, nt, F);
    fill(oebh, oe_bh, 144, tid, nt, F);
    fill(oebo, oe_bo, 48, tid, nt, F);
    fillT(aW0To, (const u16*)att_W0 + (F?512:256), 16, 16, 16, tid, nt, F);  // obj rows 16..31
    fill (ab0, att_b0, 16, tid, nt, F);
    for (int s = 0; s < 7; s++)
        fillT(rW0To + s*128, (const u16*)rel_W0 + (F?(s*512+256):(s*256+128)), 16, 8, 8, tid, nt, F);  // obj rows
    __syncthreads();

    // ---------------- phase 0b: obj embeddings (14 units = 2b x 7s) ----------------
    if (tid < 14){
        int b1 = tid / 7, s = tid % 7;
        float o[16];
        if (s < 3){
            int b = blk*2 + b1;
            float x0 = ldg(envs, b*9+3*s, F), x1 = ldg(envs, b*9+3*s+1, F), x2 = ldg(envs, b*9+3*s+2, F);
            float h[16], h2[16];
            #pragma unroll
            for (int i = 0; i < 16; i++){
                float a = oeb0[s*16+i] + x0*oeW0T[s*48+i*3] + x1*oeW0T[s*48+i*3+1] + x2*oeW0T[s*48+i*3+2];
                h[i] = elu_f(a);
            }
            for (int l = 0; l < 3; l++){
                #pragma unroll
                for (int i = 0; i < 16; i++){
                    float a = oebh[(s*3+l)*16+i];
                    #pragma unroll
                    for (int k = 0; k < 16; k++) a += h[k]*oeWhT[((s*3+l)*16+i)*16+k];
                    h2[i] = elu_f(a);
                }
                #pragma unroll
                for (int i = 0; i < 16; i++) h[i] = h2[i];
            }
            #pragma unroll
            for (int i = 0; i < 16; i++){
                float a = oebo[s*16+i];
                #pragma unroll
                for (int k = 0; k < 16; k++) a += h[k]*oeWoT[(s*16+i)*16+k];
                o[i] = a;                       // linear output layer
            }
        } else {
            #pragma unroll
            for (int i = 0; i < 16; i++) o[i] = ldg(null_embed, (s-3)*16 + i, F);
        }
        #pragma unroll
        for (int i = 0; i < 16; i++) objE[(b1*7+s)*16 + i] = o[i];
    }
    __syncthreads();

    // ---------------- phase 0c: E_att, E_rel, base_xi (2b) ----------------
    for (int idx = tid; idx < 224; idx += nt){      // idx = b1*112 + s*16 + i
        int r = idx % 112, i = r % 16;
        int os = (idx / 16) * 16;
        float a = ab0[i];
        #pragma unroll
        for (int k = 0; k < 16; k++) a += objE[os + k]*aW0To[i*16+k];
        E_att[idx] = a;
    }
    for (int idx = tid; idx < 112; idx += nt){      // idx = b1*56 + s*8 + i
        int r = idx % 56, s = r / 8, i = r % 8;
        int b1 = idx / 56;
        float a = ldg(rel_b0, s*8+i, F);
        #pragma unroll
        for (int k = 0; k < 16; k++) a += objE[(b1*7+s)*16 + k]*rW0To[(s*8+i)*16+k];
        E_rel[idx] = a;
    }
    for (int idx = tid; idx < 96; idx += nt){       // idx = b1*48 + g
        int b1 = idx / 48, g = idx % 48;
        float a = ldg(gru0_bi, g, F) + (g < 32 ? ldg(gru0_bh, g, F) : 0.f);
        for (int s = 0; s < 7; s++){
            int wb = g*128 + 16 + s*16;
            #pragma unroll
            for (int k = 0; k < 16; k++) a += objE[(b1*7+s)*16 + k]*ldg(gru0_Wi, wb+k, F);
        }
        base_xi[idx] = a;
    }

    // ------ scan persistent state: ONLY hp0/hp1 (lane j owns h[j] of its group) ------
    const int lj = ln & 15;
    const int gbase = ln & 48;          // group base within wave (0 or 16 for ln<32)
    float hp0 = 0.f, hp1 = 0.f;
    if (wid == 0 && ln < 32){
        hp0 = ldg(init_h, lj, F);
        hp1 = ldg(init_h, 16 + lj, F);
    }
    // MLP slot mapping: mtid in [0,192): b1p = mtid/96, tl = mtid%96
    const int mtid = tid - 64;
    const int b1p = (wid >= 1) ? (mtid / 96) : 0;
    const int tl  = (wid >= 1) ? (mtid % 96) : 0;
    const int bb  = blk*2 + b1p;
    __syncthreads();   // one-time region in uni dead -> becomes pipeline buffers

    // pipeline: iter c — MLP waves: phase3(c-2) then phase1(c); scan wave: chunk c-1
    for (int c = 0; c <= NCHK+1; c++){
        if (wid == 0){
            // ---------------- scan: 2 b (lanes 0-31), chunk c-1 ----------------
            if (ln < 32 && c >= 1 && c <= NCHK){
                const int cs = c-1;
                const int tcs = csize(cs);
                const _Float16* xb = (cs&1) ? bufB : bufA;
                _Float16*       gb = (cs&1) ? gruB : gruA;
                // all-gates weights for this lane's j: 144 regs, chunk-local,
                // loaded straight from global (L2-resident; amortized over 96 steps)
                float w0r[16], w0z[16], w0n[16], wi1r[16], wi1z[16], wi1n[16], wh1r[16], wh1z[16], wh1n[16];
                #pragma unroll
                for (int k = 0; k < 16; k++){
                    w0r[k]  = ldg(gru0_Wh, lj*16+k, F);
                    w0z[k]  = ldg(gru0_Wh, (16+lj)*16+k, F);
                    w0n[k]  = ldg(gru0_Wh, (32+lj)*16+k, F);
                    wi1r[k] = ldg(gru1_Wi, lj*16+k, F);
                    wi1z[k] = ldg(gru1_Wi, (16+lj)*16+k, F);
                    wi1n[k] = ldg(gru1_Wi, (32+lj)*16+k, F);
                    wh1r[k] = ldg(gru1_Wh, lj*16+k, F);
                    wh1z[k] = ldg(gru1_Wh, (16+lj)*16+k, F);
                    wh1n[k] = ldg(gru1_Wh, (32+lj)*16+k, F);
                }
                const float c0  = g0bhn[lj];
                const float cr  = g1bi48[lj]    + g1bh48[lj];
                const float cz  = g1bi48[16+lj] + g1bh48[16+lj];
                const float can = g1bi48[32+lj];
                const float cbn = g1bh48[32+lj];
                // rebuild h vectors from per-lane scalars
                float h0[16], h1[16];
                #pragma unroll
                for (int k = 0; k < 16; k++){ h0[k] = __shfl(hp0, gbase + k); h1[k] = __shfl(hp1, gbase + k); }
                const int grp = ln >> 4;            // 0 or 1
                // prefetch step 0
                int sb = (grp*96 + 0)*48 + lj;
                float xr = (float)xb[sb], xz = (float)xb[sb+16], xn = (float)xb[sb+32];
                for (int s = 0; s < tcs; s++){
                    // prefetch next step's x
                    float xrn = 0.f, xzn = 0.f, xnn2 = 0.f;
                    if (s+1 < tcs){
                        int sb2 = (grp*96 + s+1)*48 + lj;
                        xrn = (float)xb[sb2]; xzn = (float)xb[sb2+16]; xnn2 = (float)xb[sb2+32];
                    }
                    // layer 0 (all gates local to lane)
                    float hr = 0.f, hz = 0.f, hn = c0;
                    #pragma unroll
                    for (int k = 0; k < 16; k++){ hr += h0[k]*w0r[k]; hz += h0[k]*w0z[k]; hn += h0[k]*w0n[k]; }
                    float r = sigm(xr + hr);
                    float z = sigm(xz + hz);
                    float n = tanh_f(xn + r*hn);
                    float h0n = (1.f - z)*n + z*hp0;
                    hp0 = h0n;
                    #pragma unroll
                    for (int k = 0; k < 16; k++) h0[k] = __shfl(h0n, gbase + k);
                    // layer 1
                    float ar = cr, az = cz, an = can, br = 0.f, bz = 0.f, bn = cbn;
                    #pragma unroll
                    for (int k = 0; k < 16; k++){
                        ar += h0[k]*wi1r[k]; az += h0[k]*wi1z[k]; an += h0[k]*wi1n[k];
                        br += h1[k]*wh1r[k]; bz += h1[k]*wh1z[k]; bn += h1[k]*wh1n[k];
                    }
                    float r1 = sigm(ar + br);
                    float z1 = sigm(az + bz);
                    float n1 = tanh_f(an + r1*bn);
                    float h1n = (1.f - z1)*n1 + z1*hp1;
                    hp1 = h1n;
                    gb[(grp*96 + s)*16 + lj] = (_Float16)h1n;
                    #pragma unroll
                    for (int k = 0; k < 16; k++) h1[k] = __shfl(h1n, gbase + k);
                    xr = xrn; xz = xzn; xn = xnn2;
                }
            }
        } else {
            // ---------------- phase 3 for chunk c-2 (wvv fused into facc) ----------------
            if (c >= 2){
                const int cp = c-2;
                const int tcp = csize(cp);
                if (tl < tcp){
                    const _Float16* gb = (cp&1) ? gruB : gruA;
                    const _Float16* cb = (cp&1) ? cscB : cscA;
                    const float invv = ((cp&1) ? invB : invA)[b1p*96 + tl];
                    float g[16];
                    #pragma unroll
                    for (int i = 0; i < 16; i++) g[i] = (float)gb[(b1p*96 + tl)*16 + i];
                    float facc[4];
                    #pragma unroll
                    for (int cc = 0; cc < 4; cc++){
                        float a = fb0[cc];
                        #pragma unroll
                        for (int k = 0; k < 16; k++) a += g[k]*fW0T[cc*72+k];
                        facc[cc] = a;
                    }
                    #pragma unroll 1
                    for (int s = 0; s < 7; s++){          // ROLLED: cap register pressure
                        const float* ep = E_rel + (b1p*7+s)*8;   // includes rel_b0
                        float p1a[8], p2a[8];
                        #pragma unroll
                        for (int i = 0; i < 8; i++){
                            float a = ep[i];
                            #pragma unroll
                            for (int k = 0; k < 16; k++) a += g[k]*rW0T[(s*8+i)*16+k];
                            p1a[i] = elu_f(a);
                        }
                        #pragma unroll
                        for (int i = 0; i < 8; i++){
                            float a = rbh[s*8+i];
                            #pragma unroll
                            for (int k = 0; k < 8; k++) a += p1a[k]*rWhT[(s*8+i)*8+k];
                            p2a[i] = elu_f(a);
                        }
                        float w = (float)cb[(b1p*7+s)*96 + tl] * invv;
                        #pragma unroll
                        for (int i = 0; i < 8; i++){
                            float a = rbo[s*8+i];
                            #pragma unroll
                            for (int k = 0; k < 8; k++) a += p2a[k]*rWoT[(s*8+i)*8+k];
                            float val = a*w;
                            #pragma unroll
                            for (int cc = 0; cc < 4; cc++) facc[cc] += val*fW0T[cc*72+16+s*8+i];
                        }
                    }
                    float f1[4], f2[4], o[4];
                    #pragma unroll
                    for (int cc = 0; cc < 4; cc++) f1[cc] = elu_f(facc[cc]);
                    #pragma unroll
                    for (int cc = 0; cc < 4; cc++){
                        float a = fbh[cc];
                        #pragma unroll
                        for (int k = 0; k < 4; k++) a += f1[k]*fWhT[cc*4+k];
                        f2[cc] = elu_f(a);
                    }
                    #pragma unroll
                    for (int cc = 0; cc < 4; cc++){
                        float a = fbo[cc];
                        #pragma unroll
                        for (int k = 0; k < 4; k++) a += f2[k]*fWoT[cc*4+k];
                        o[cc] = a;
                    }
                    size_t ofs = ((size_t)bb*TLEN + (cp*TCW + tl))*4;   // out (B,T,4)
                    if (F){
                        float4 v; v.x = o[0]; v.y = o[1]; v.z = o[2]; v.w = o[3];
                        *(float4*)((float*)out + ofs) = v;
                    } else {
                        u32 lo = (u32)f2bf(o[0]) | ((u32)f2bf(o[1]) << 16);
                        u32 hi = (u32)f2bf(o[2]) | ((u32)f2bf(o[3]) << 16);
                        *(uint2*)((u16*)out + ofs) = make_uint2(lo, hi);
                    }
                }
            }
            // ---------------- phase 1 for chunk c (xi projection BEFORE att) ----------------
            if (c < NCHK){
                const int tcc = csize(c);
                if (tl < tcc){
                    _Float16* xb = (c&1) ? bufB : bufA;
                    _Float16* cb = (c&1) ? cscB : cscA;
                    float*   ivb = (c&1) ? invB : invA;
                    const int t = c*TCW + tl;
                    int sbase = ((int)bb*TLEN + t)*4;    // states (B,T,4)
                    float x0 = ldg(states, sbase+0, F), x1 = ldg(states, sbase+1, F);
                    float x2 = ldg(states, sbase+2, F), x3 = ldg(states, sbase+3, F);
                    float h[16], h2[16];
                    #pragma unroll
                    for (int i = 0; i < 16; i++){
                        float a = sb0[i] + x0*sW0T[i*4] + x1*sW0T[i*4+1] + x2*sW0T[i*4+2] + x3*sW0T[i*4+3];
                        h[i] = fmaxf(a, 0.f);
                    }
                    for (int l = 0; l < 3; l++){
                        #pragma unroll
                        for (int i = 0; i < 16; i++){
                            float a = sbh[l*16+i];
                            #pragma unroll
                            for (int k = 0; k < 16; k++) a += h[k]*sWhT[(l*16+i)*16+k];
                            h2[i] = fmaxf(a, 0.f);
                        }
                        #pragma unroll
                        for (int i = 0; i < 16; i++) h[i] = h2[i];
                    }
                    float se[16];
                    #pragma unroll
                    for (int i = 0; i < 16; i++){
                        float a = sbo[i];
                        #pragma unroll
                        for (int k = 0; k < 16; k++) a += h[k]*sWoT[i*16+k];
                        se[i] = a;
                    }
                    // xi projection first: after this, se only needed for satt
                    #pragma unroll 4
                    for (int g = 0; g < 48; g++){
                        float a = base_xi[b1p*48 + g];
                        #pragma unroll
                        for (int k = 0; k < 16; k++) a += se[k]*wi0se[g*16+k];
                        xb[(b1p*96 + tl)*48 + g] = (_Float16)a;
                    }
                    float satt[16];
                    #pragma unroll
                    for (int i = 0; i < 16; i++){
                        float a = 0.f;
                        #pragma unroll
                        for (int k = 0; k < 16; k++) a += se[k]*aW0T[i*16+k];
                        satt[i] = a;
                    }
                    // att slots ROLLED; unnormalized exp accumulated (scores are O(1))
                    float sum = 0.f;
                    #pragma unroll 1
                    for (int s = 0; s < 7; s++){
                        const float* ep = E_att + (b1p*7+s)*16;   // includes att_b0
                        float a1[16], a2[16];
                        #pragma unroll
                        for (int i = 0; i < 16; i++) a1[i] = elu_f(satt[i] + ep[i]);
                        #pragma unroll
                        for (int i = 0; i < 16; i++){
                            float a = abh[i];
                            #pragma unroll
                            for (int k = 0; k < 16; k++) a += a1[k]*aWhT[i*16+k];
                            a2[i] = elu_f(a);
                        }
                        #pragma unroll
                        for (int i = 0; i < 16; i++){
                            float a = abh[16+i];
                            #pragma unroll
                            for (int k = 0; k < 16; k++) a += a2[k]*aWhT[256 + i*16+k];
                            a1[i] = elu_f(a);
                        }
                        float a = abo_s[0];
                        #pragma unroll
                        for (int k = 0; k < 16; k++) a += a1[k]*aWo[k];
                        float ex = fexp2(a*LOG2E);
                        cb[(b1p*7+(6-s))*96 + tl] = (_Float16)ex;   // flip
                        sum += ex;
                    }
                    ivb[b1p*96 + tl] = frcp(sum);
                }
            }
        }
        __syncthreads();
    }
}

extern "C" void kernel_launch(void* const* d_in, const int* in_sizes, int n_in,
                              void* d_out, int out_size, void* d_ws, size_t ws_size,
                              hipStream_t stream)
{
    (void)in_sizes; (void)n_in; (void)out_size; (void)d_ws; (void)ws_size;
    fused<<<dim3(512), dim3(256), 0, stream>>>(
        d_in[0],  d_in[1],
        d_in[2],  d_in[3],  d_in[4],  d_in[5],  d_in[6],  d_in[7],
        d_in[8],  d_in[9],  d_in[10], d_in[11], d_in[12], d_in[13],
        d_in[14], d_in[15],
        d_in[16], d_in[17], d_in[18], d_in[19], d_in[20], d_in[21],
        d_in[22], d_in[23], d_in[24], d_in[25],
        d_in[26], d_in[27], d_in[28], d_in[29],
        d_in[30], d_in[31], d_in[32], d_in[33], d_in[34], d_in[35],
        d_in[36], d_in[37], d_in[38], d_in[39], d_in[40], d_in[41],
        d_out);
}

// Round 18
// 784.918 us; speedup vs baseline: 1.4127x; 1.4127x over previous
//
#include <hip/hip_runtime.h>
#include <hip/hip_bf16.h>
#include <hip/hip_fp16.h>
#include <stdint.h>

#define TLEN 512
#define TCW 48
#define NCHK 11                       // 10 chunks of 48 + 1 of 32
__device__ __forceinline__ int csize(int i){ return (i == 10) ? 32 : 48; }

typedef unsigned short u16;
typedef unsigned int u32;

__device__ __forceinline__ float b2f(u16 u){ union{u32 i; float f;} v; v.i = ((u32)u)<<16; return v.f; }
__device__ __forceinline__ u16 f2bf(float f){
    union{float f; u32 i;} v; v.f = f;
    u32 b = v.i; b += 0x7fffu + ((b>>16)&1u);   // RNE
    return (u16)(b>>16);
}
__device__ __forceinline__ float fexp2(float x){ return __builtin_amdgcn_exp2f(x); }
__device__ __forceinline__ float frcp(float x){ return __builtin_amdgcn_rcpf(x); }
#define LOG2E 1.4426950408889634f
__device__ __forceinline__ float elu_f(float x){ return x > 0.f ? x : fexp2(x*LOG2E) - 1.f; }
__device__ __forceinline__ float sigm(float x){ return frcp(1.f + fexp2(-LOG2E*x)); }
__device__ __forceinline__ float tanh_f(float x){ return 1.f - 2.f*frcp(1.f + fexp2((2.f*LOG2E)*x)); }

// compile-time dtype load (TF=true -> f32, else bf16). Uniform indices -> s_load.
template<bool TF>
__device__ __forceinline__ float wload(const void* p, int i){
    if constexpr (TF) return ((const float*)p)[i];
    else return b2f(((const u16*)p)[i]);
}

__device__ void fillg(float* dst, const void* src, int n, int tid, int nt, bool F){
    for (int i = tid; i < n; i += nt) dst[i] = F ? ((const float*)src)[i] : b2f(((const u16*)src)[i]);
}
// transposed: dst[i*K+k] = src[k*stride+i]
__device__ void fillTg(float* dst, const void* src, int K, int I, int stride, int tid, int nt, bool F){
    for (int idx = tid; idx < K*I; idx += nt){
        int i = idx / K, k = idx % K;
        dst[idx] = F ? ((const float*)src)[k*stride + i] : b2f(((const u16*)src)[k*stride + i]);
    }
}

__global__ void detect(const void* se_W0, int* flag){
    const u16* p = (const u16*)se_W0;
    int ok = 1;
    #pragma unroll
    for (int k = 0; k < 8; k++){
        float v = fabsf(b2f(p[2*k]));
        ok &= (v > 1e-12f && v < 16.f) ? 1 : 0;
    }
    *flag = ok ? 0 : 1;   // 1 = float32
}

// 256 threads, 4 waves: wave 0 = GRU scan for 4 b (16 lanes/b, all gates per lane),
// waves 1-3 = MLP (192 threads = 4b x 48t slots). Block owns 4 b; 256 blocks.
template<bool TF>
__global__ __launch_bounds__(256,1) void fused(
    const int* flagp,
    const void* envs, const void* states,
    const void* se_W0, const void* se_b0, const void* se_Wh, const void* se_bh, const void* se_Wo, const void* se_bo,
    const void* oe_W0, const void* oe_b0, const void* oe_Wh, const void* oe_bh, const void* oe_Wo, const void* oe_bo,
    const void* null_embed, const void* init_h,
    const void* att_W0, const void* att_b0, const void* att_Wh, const void* att_bh, const void* att_Wo, const void* att_bo,
    const void* gru0_Wi, const void* gru0_Wh, const void* gru0_bi, const void* gru0_bh,
    const void* gru1_Wi, const void* gru1_Wh, const void* gru1_bi, const void* gru1_bh,
    const void* rel_W0, const void* rel_b0, const void* rel_Wh, const void* rel_bh, const void* rel_Wo, const void* rel_bo,
    const void* fin_W0, const void* fin_b0, const void* fin_Wh, const void* fin_bh, const void* fin_Wo, const void* fin_bo,
    void* out)
{
    if ((*(volatile const int*)flagp != 0) != TF) return;

    __shared__ float E_att[448], E_rel[224], base_xi[192];
    __shared__ float g0bhn[16], g1bi48[48], g1bh48[48];   // scan biases (lane-varying reads)
    __shared__ float uni[14016];                           // one-time staging, then pipeline buffers

    const int tid = threadIdx.x, nt = 256;
    const int blk = blockIdx.x;
    const int wid = tid >> 6, ln = tid & 63;

    _Float16* bufA = (_Float16*)(uni);           // 4b x 48t x 48 = 9216 h
    _Float16* bufB = (_Float16*)(uni + 4608);
    _Float16* gruA = (_Float16*)(uni + 9216);    // 4b x 48t x 16 = 3072 h
    _Float16* gruB = (_Float16*)(uni + 10752);
    _Float16* cscA = (_Float16*)(uni + 12288);   // 4b x 7s x 48t = 1344 h (unnormalized exp)
    _Float16* cscB = (_Float16*)(uni + 12960);
    float*    invA = uni + 13632;                // 4b x 48t = 192 f
    float*    invB = uni + 13824;

    // ---------------- phase 0a: small scan-bias staging ----------------
    fillg(g0bhn, (const u16*)gru0_bh + (TF?64:32), 16, tid, nt, TF);  // bh0_n (elem off 32)
    fillg(g1bi48, gru1_bi, 48, tid, nt, TF);
    fillg(g1bh48, gru1_bh, 48, tid, nt, TF);
    // one-time buffers inside uni (4848 floats, dead before pipeline starts)
    float* oeW0T = uni;         // 144
    float* oeb0  = uni + 144;   // 48
    float* oeWhT = uni + 192;   // 2304
    float* oebh  = uni + 2496;  // 144
    float* oeWoT = uni + 2640;  // 768
    float* oebo  = uni + 3408;  // 48
    float* aW0To = uni + 3456;  // 256
    float* ab0   = uni + 3712;  // 16
    float* rW0To = uni + 3728;  // 896
    float* objE  = uni + 4624;  // 448 (4b x 7s x 16)
    for (int s = 0; s < 3; s++){
        fillTg(oeW0T + s*48, (const u16*)oe_W0 + (TF?s*96:s*48), 3, 16, 16, tid, nt, TF);
        for (int l = 0; l < 3; l++)
            fillTg(oeWhT + (s*3+l)*256, (const u16*)oe_Wh + (TF?(s*3+l)*512:(s*3+l)*256), 16, 16, 16, tid, nt, TF);
        fillTg(oeWoT + s*256, (const u16*)oe_Wo + (TF?s*512:s*256), 16, 16, 16, tid, nt, TF);
    }
    fillg(oeb0, oe_b0, 48, tid, nt, TF);
    fillg(oebh, oe_bh, 144, tid, nt, TF);
    fillg(oebo, oe_bo, 48, tid, nt, TF);
    fillTg(aW0To, (const u16*)att_W0 + (TF?512:256), 16, 16, 16, tid, nt, TF);  // obj rows 16..31
    fillg(ab0, att_b0, 16, tid, nt, TF);
    for (int s = 0; s < 7; s++)
        fillTg(rW0To + s*128, (const u16*)rel_W0 + (TF?(s*512+256):(s*256+128)), 16, 8, 8, tid, nt, TF);
    __syncthreads();

    // ---------------- phase 0b: obj embeddings (28 units = 4b x 7s) ----------------
    if (tid < 28){
        int b1 = tid / 7, s = tid % 7;
        float o[16];
        if (s < 3){
            int b = blk*4 + b1;
            float x0 = wload<TF>(envs, b*9+3*s), x1 = wload<TF>(envs, b*9+3*s+1), x2 = wload<TF>(envs, b*9+3*s+2);
            float h[16], h2[16];
            #pragma unroll
            for (int i = 0; i < 16; i++){
                float a = oeb0[s*16+i] + x0*oeW0T[s*48+i*3] + x1*oeW0T[s*48+i*3+1] + x2*oeW0T[s*48+i*3+2];
                h[i] = elu_f(a);
            }
            for (int l = 0; l < 3; l++){
                #pragma unroll
                for (int i = 0; i < 16; i++){
                    float a = oebh[(s*3+l)*16+i];
                    #pragma unroll
                    for (int k = 0; k < 16; k++) a += h[k]*oeWhT[((s*3+l)*16+i)*16+k];
                    h2[i] = elu_f(a);
                }
                #pragma unroll
                for (int i = 0; i < 16; i++) h[i] = h2[i];
            }
            #pragma unroll
            for (int i = 0; i < 16; i++){
                float a = oebo[s*16+i];
                #pragma unroll
                for (int k = 0; k < 16; k++) a += h[k]*oeWoT[(s*16+i)*16+k];
                o[i] = a;                       // linear output layer
            }
        } else {
            #pragma unroll
            for (int i = 0; i < 16; i++) o[i] = wload<TF>(null_embed, (s-3)*16 + i);
        }
        #pragma unroll
        for (int i = 0; i < 16; i++) objE[(b1*7+s)*16 + i] = o[i];
    }
    __syncthreads();

    // ---------------- phase 0c: E_att, E_rel, base_xi (4b) ----------------
    for (int idx = tid; idx < 448; idx += nt){
        int r = idx % 112, i = r % 16;
        int os = (idx / 16) * 16;
        float a = ab0[i];
        #pragma unroll
        for (int k = 0; k < 16; k++) a += objE[os + k]*aW0To[i*16+k];
        E_att[idx] = a;
    }
    for (int idx = tid; idx < 224; idx += nt){
        int r = idx % 56, s = r / 8, i = r % 8;
        int b1 = idx / 56;
        float a = wload<TF>(rel_b0, s*8+i);
        #pragma unroll
        for (int k = 0; k < 16; k++) a += objE[(b1*7+s)*16 + k]*rW0To[(s*8+i)*16+k];
        E_rel[idx] = a;
    }
    for (int idx = tid; idx < 192; idx += nt){
        int b1 = idx / 48, g = idx % 48;
        float a = wload<TF>(gru0_bi, g) + (g < 32 ? wload<TF>(gru0_bh, g) : 0.f);
        for (int s = 0; s < 7; s++){
            int wb = g*128 + 16 + s*16;
            #pragma unroll
            for (int k = 0; k < 16; k++) a += objE[(b1*7+s)*16 + k]*wload<TF>(gru0_Wi, wb+k);
        }
        base_xi[idx] = a;
    }

    // ------ scan persistent state: ONLY hp0/hp1 ------
    const int lj = ln & 15;
    const int gbase = ln & 48;
    float hp0 = 0.f, hp1 = 0.f;
    if (wid == 0){
        hp0 = wload<TF>(init_h, lj);
        hp1 = wload<TF>(init_h, 16 + lj);
    }
    const int mtid = tid - 64;
    const int b1p = (wid >= 1) ? (mtid / 48) : 0;
    const int tl  = (wid >= 1) ? (mtid % 48) : 0;
    const int bb  = blk*4 + b1p;
    __syncthreads();   // one-time region dead -> pipeline buffers live

    for (int c = 0; c <= NCHK+1; c++){
        if (wid == 0){
            // ---------------- scan wave: 4 b, chunk c-1 ----------------
            if (c >= 1 && c <= NCHK){
                const int cs = c-1;
                const int tcs = csize(cs);
                const _Float16* xb = (cs&1) ? bufB : bufA;
                _Float16*       gb = (cs&1) ? gruB : gruA;
                float w0r[16], w0z[16], w0n[16], wi1r[16], wi1z[16], wi1n[16], wh1r[16], wh1z[16], wh1n[16];
                #pragma unroll
                for (int k = 0; k < 16; k++){
                    w0r[k]  = wload<TF>(gru0_Wh, lj*16+k);
                    w0z[k]  = wload<TF>(gru0_Wh, (16+lj)*16+k);
                    w0n[k]  = wload<TF>(gru0_Wh, (32+lj)*16+k);
                    wi1r[k] = wload<TF>(gru1_Wi, lj*16+k);
                    wi1z[k] = wload<TF>(gru1_Wi, (16+lj)*16+k);
                    wi1n[k] = wload<TF>(gru1_Wi, (32+lj)*16+k);
                    wh1r[k] = wload<TF>(gru1_Wh, lj*16+k);
                    wh1z[k] = wload<TF>(gru1_Wh, (16+lj)*16+k);
                    wh1n[k] = wload<TF>(gru1_Wh, (32+lj)*16+k);
                }
                const float c0  = g0bhn[lj];
                const float cr  = g1bi48[lj]    + g1bh48[lj];
                const float cz  = g1bi48[16+lj] + g1bh48[16+lj];
                const float can = g1bi48[32+lj];
                const float cbn = g1bh48[32+lj];
                float h0[16], h1[16];
                #pragma unroll
                for (int k = 0; k < 16; k++){ h0[k] = __shfl(hp0, gbase + k); h1[k] = __shfl(hp1, gbase + k); }
                const int grp = ln >> 4;
                int sb = (grp*48 + 0)*48 + lj;
                float xr = (float)xb[sb], xz = (float)xb[sb+16], xn = (float)xb[sb+32];
                for (int s = 0; s < tcs; s++){
                    float xrn = 0.f, xzn = 0.f, xnn2 = 0.f;
                    if (s+1 < tcs){
                        int sb2 = (grp*48 + s+1)*48 + lj;
                        xrn = (float)xb[sb2]; xzn = (float)xb[sb2+16]; xnn2 = (float)xb[sb2+32];
                    }
                    float hr = 0.f, hz = 0.f, hn = c0;
                    #pragma unroll
                    for (int k = 0; k < 16; k++){ hr += h0[k]*w0r[k]; hz += h0[k]*w0z[k]; hn += h0[k]*w0n[k]; }
                    float r = sigm(xr + hr);
                    float z = sigm(xz + hz);
                    float n = tanh_f(xn + r*hn);
                    float h0n = (1.f - z)*n + z*hp0;
                    hp0 = h0n;
                    #pragma unroll
                    for (int k = 0; k < 16; k++) h0[k] = __shfl(h0n, gbase + k);
                    float ar = cr, az = cz, an = can, br = 0.f, bz = 0.f, bn = cbn;
                    #pragma unroll
                    for (int k = 0; k < 16; k++){
                        ar += h0[k]*wi1r[k]; az += h0[k]*wi1z[k]; an += h0[k]*wi1n[k];
                        br += h1[k]*wh1r[k]; bz += h1[k]*wh1z[k]; bn += h1[k]*wh1n[k];
                    }
                    float r1 = sigm(ar + br);
                    float z1 = sigm(az + bz);
                    float n1 = tanh_f(an + r1*bn);
                    float h1n = (1.f - z1)*n1 + z1*hp1;
                    hp1 = h1n;
                    gb[(grp*48 + s)*16 + lj] = (_Float16)h1n;
                    #pragma unroll
                    for (int k = 0; k < 16; k++) h1[k] = __shfl(h1n, gbase + k);
                    xr = xrn; xz = xzn; xn = xnn2;
                }
            }
        } else {
            // ---------------- phase 3 for chunk c-2 (k-outer, scalar weights) ----------------
            if (c >= 2){
                const int cp = c-2;
                const int tcp = csize(cp);
                if (tl < tcp){
                    const _Float16* gb = (cp&1) ? gruB : gruA;
                    const _Float16* cb = (cp&1) ? cscB : cscA;
                    const float invv = ((cp&1) ? invB : invA)[b1p*48 + tl];
                    float g[16];
                    #pragma unroll
                    for (int i = 0; i < 16; i++) g[i] = (float)gb[(b1p*48 + tl)*16 + i];
                    float facc[4];
                    #pragma unroll
                    for (int cc = 0; cc < 4; cc++) facc[cc] = wload<TF>(fin_b0, cc);
                    #pragma unroll
                    for (int k = 0; k < 16; k++){
                        float gv = g[k];
                        #pragma unroll
                        for (int cc = 0; cc < 4; cc++) facc[cc] += gv*wload<TF>(fin_W0, k*4+cc);
                    }
                    #pragma unroll 1
                    for (int s = 0; s < 7; s++){
                        const float* ep = E_rel + (b1p*7+s)*8;
                        float p1a[8], p2a[8];
                        #pragma unroll
                        for (int i = 0; i < 8; i++) p1a[i] = ep[i];
                        #pragma unroll
                        for (int k = 0; k < 16; k++){
                            float gv = g[k];
                            #pragma unroll
                            for (int i = 0; i < 8; i++) p1a[i] += gv*wload<TF>(rel_W0, s*256 + k*8 + i);
                        }
                        #pragma unroll
                        for (int i = 0; i < 8; i++) p1a[i] = elu_f(p1a[i]);
                        #pragma unroll
                        for (int i = 0; i < 8; i++) p2a[i] = wload<TF>(rel_bh, s*8+i);
                        #pragma unroll
                        for (int k = 0; k < 8; k++){
                            float pv = p1a[k];
                            #pragma unroll
                            for (int i = 0; i < 8; i++) p2a[i] += pv*wload<TF>(rel_Wh, s*64 + k*8 + i);
                        }
                        #pragma unroll
                        for (int i = 0; i < 8; i++) p2a[i] = elu_f(p2a[i]);
                        float w = (float)cb[(b1p*7+s)*48 + tl] * invv;
                        float ro[8];
                        #pragma unroll
                        for (int i = 0; i < 8; i++) ro[i] = wload<TF>(rel_bo, s*8+i);
                        #pragma unroll
                        for (int k = 0; k < 8; k++){
                            float pv = p2a[k];
                            #pragma unroll
                            for (int i = 0; i < 8; i++) ro[i] += pv*wload<TF>(rel_Wo, s*64 + k*8 + i);
                        }
                        #pragma unroll
                        for (int i = 0; i < 8; i++){
                            float val = ro[i]*w;
                            #pragma unroll
                            for (int cc = 0; cc < 4; cc++) facc[cc] += val*wload<TF>(fin_W0, (16+s*8+i)*4+cc);
                        }
                    }
                    float f1[4], f2[4], o[4];
                    #pragma unroll
                    for (int cc = 0; cc < 4; cc++) f1[cc] = elu_f(facc[cc]);
                    #pragma unroll
                    for (int cc = 0; cc < 4; cc++) f2[cc] = wload<TF>(fin_bh, cc);
                    #pragma unroll
                    for (int k = 0; k < 4; k++){
                        float fv = f1[k];
                        #pragma unroll
                        for (int cc = 0; cc < 4; cc++) f2[cc] += fv*wload<TF>(fin_Wh, k*4+cc);
                    }
                    #pragma unroll
                    for (int cc = 0; cc < 4; cc++) f2[cc] = elu_f(f2[cc]);
                    #pragma unroll
                    for (int cc = 0; cc < 4; cc++) o[cc] = wload<TF>(fin_bo, cc);
                    #pragma unroll
                    for (int k = 0; k < 4; k++){
                        float fv = f2[k];
                        #pragma unroll
                        for (int cc = 0; cc < 4; cc++) o[cc] += fv*wload<TF>(fin_Wo, k*4+cc);
                    }
                    size_t ofs = ((size_t)bb*TLEN + (cp*TCW + tl))*4;   // out (B,T,4)
                    if (TF){
                        float4 v; v.x = o[0]; v.y = o[1]; v.z = o[2]; v.w = o[3];
                        *(float4*)((float*)out + ofs) = v;
                    } else {
                        u32 lo = (u32)f2bf(o[0]) | ((u32)f2bf(o[1]) << 16);
                        u32 hi = (u32)f2bf(o[2]) | ((u32)f2bf(o[3]) << 16);
                        *(uint2*)((u16*)out + ofs) = make_uint2(lo, hi);
                    }
                }
            }
            // ---------------- phase 1 for chunk c (k-outer, scalar weights) ----------------
            if (c < NCHK){
                const int tcc = csize(c);
                if (tl < tcc){
                    _Float16* xb = (c&1) ? bufB : bufA;
                    _Float16* cb = (c&1) ? cscB : cscA;
                    float*   ivb = (c&1) ? invB : invA;
                    const int t = c*TCW + tl;
                    int sbase = ((int)bb*TLEN + t)*4;    // states (B,T,4)
                    float x[4];
                    #pragma unroll
                    for (int k = 0; k < 4; k++) x[k] = wload<TF>(states, sbase+k);
                    float h[16], h2[16];
                    #pragma unroll
                    for (int i = 0; i < 16; i++) h[i] = wload<TF>(se_b0, i);
                    #pragma unroll
                    for (int k = 0; k < 4; k++){
                        float xv = x[k];
                        #pragma unroll
                        for (int i = 0; i < 16; i++) h[i] += xv*wload<TF>(se_W0, k*16+i);
                    }
                    #pragma unroll
                    for (int i = 0; i < 16; i++) h[i] = fmaxf(h[i], 0.f);
                    for (int l = 0; l < 3; l++){
                        #pragma unroll
                        for (int i = 0; i < 16; i++) h2[i] = wload<TF>(se_bh, l*16+i);
                        #pragma unroll
                        for (int k = 0; k < 16; k++){
                            float hv = h[k];
                            #pragma unroll
                            for (int i = 0; i < 16; i++) h2[i] += hv*wload<TF>(se_Wh, l*256 + k*16 + i);
                        }
                        #pragma unroll
                        for (int i = 0; i < 16; i++) h[i] = fmaxf(h2[i], 0.f);
                    }
                    float se[16];
                    #pragma unroll
                    for (int i = 0; i < 16; i++) se[i] = wload<TF>(se_bo, i);
                    #pragma unroll
                    for (int k = 0; k < 16; k++){
                        float hv = h[k];
                        #pragma unroll
                        for (int i = 0; i < 16; i++) se[i] += hv*wload<TF>(se_Wo, k*16+i);
                    }
                    // xi projection (k-inner contiguous in gru0_Wi row)
                    #pragma unroll 4
                    for (int g = 0; g < 48; g++){
                        float a = base_xi[b1p*48 + g];
                        #pragma unroll
                        for (int k = 0; k < 16; k++) a += se[k]*wload<TF>(gru0_Wi, g*128 + k);
                        xb[(b1p*48 + tl)*48 + g] = (_Float16)a;
                    }
                    float satt[16];
                    #pragma unroll
                    for (int i = 0; i < 16; i++) satt[i] = 0.f;
                    #pragma unroll
                    for (int k = 0; k < 16; k++){
                        float sv = se[k];
                        #pragma unroll
                        for (int i = 0; i < 16; i++) satt[i] += sv*wload<TF>(att_W0, k*16+i);
                    }
                    // att slots ROLLED; unnormalized exp accumulated
                    float sum = 0.f;
                    #pragma unroll 1
                    for (int s = 0; s < 7; s++){
                        const float* ep = E_att + (b1p*7+s)*16;   // includes att_b0
                        float a1[16], a2[16];
                        #pragma unroll
                        for (int i = 0; i < 16; i++) a1[i] = elu_f(satt[i] + ep[i]);
                        #pragma unroll
                        for (int i = 0; i < 16; i++) a2[i] = wload<TF>(att_bh, i);
                        #pragma unroll
                        for (int k = 0; k < 16; k++){
                            float av = a1[k];
                            #pragma unroll
                            for (int i = 0; i < 16; i++) a2[i] += av*wload<TF>(att_Wh, k*16+i);
                        }
                        #pragma unroll
                        for (int i = 0; i < 16; i++) a2[i] = elu_f(a2[i]);
                        #pragma unroll
                        for (int i = 0; i < 16; i++) a1[i] = wload<TF>(att_bh, 16+i);
                        #pragma unroll
                        for (int k = 0; k < 16; k++){
                            float av = a2[k];
                            #pragma unroll
                            for (int i = 0; i < 16; i++) a1[i] += av*wload<TF>(att_Wh, 256 + k*16+i);
                        }
                        float a = wload<TF>(att_bo, 0);
                        #pragma unroll
                        for (int k = 0; k < 16; k++) a += elu_f(a1[k])*wload<TF>(att_Wo, k);
                        float ex = fexp2(a*LOG2E);
                        cb[(b1p*7+(6-s))*48 + tl] = (_Float16)ex;   // flip
                        sum += ex;
                    }
                    ivb[b1p*48 + tl] = frcp(sum);
                }
            }
        }
        __syncthreads();
    }
}

extern "C" void kernel_launch(void* const* d_in, const int* in_sizes, int n_in,
                              void* d_out, int out_size, void* d_ws, size_t ws_size,
                              hipStream_t stream)
{
    (void)in_sizes; (void)n_in; (void)out_size; (void)ws_size;
    int* flag = (int*)d_ws;
    detect<<<dim3(1), dim3(1), 0, stream>>>(d_in[2], flag);
#define ARGS flag, d_in[0], d_in[1], d_in[2], d_in[3], d_in[4], d_in[5], d_in[6], d_in[7], \
    d_in[8], d_in[9], d_in[10], d_in[11], d_in[12], d_in[13], d_in[14], d_in[15], \
    d_in[16], d_in[17], d_in[18], d_in[19], d_in[20], d_in[21], \
    d_in[22], d_in[23], d_in[24], d_in[25], d_in[26], d_in[27], d_in[28], d_in[29], \
    d_in[30], d_in[31], d_in[32], d_in[33], d_in[34], d_in[35], \
    d_in[36], d_in[37], d_in[38], d_in[39], d_in[40], d_in[41], d_out
    fused<false><<<dim3(256), dim3(256), 0, stream>>>(ARGS);
    fused<true><<<dim3(256), dim3(256), 0, stream>>>(ARGS);
#undef ARGS
}